// Round 1
// baseline (207.626 us; speedup 1.0000x reference)
//
#include <hip/hip_runtime.h>

__device__ __forceinline__ float2 cadd(float2 a, float2 b) { return make_float2(a.x + b.x, a.y + b.y); }
__device__ __forceinline__ float2 csub(float2 a, float2 b) { return make_float2(a.x - b.x, a.y - b.y); }
__device__ __forceinline__ float2 cmul(float2 w, float2 z) {
    return make_float2(w.x * z.x - w.y * z.y, w.x * z.y + w.y * z.x);
}

// ---------------------------------------------------------------------------
// In-place butterfly network equivalent of the reference (verified by hand, n=8):
//   stage t (0..22): pairs (i, i + 2^(22-t)); z'[i] = z[i] + w*z[i+D]; z'[i+D] = z[i] - w*z[i+D]
//   w = weight[ bitrev_t(i >> (23-t)) * 2^(22-t) ]
//   final: out[o] = z[bitrev23(o)]
// Pass A: t=0..7   (addr bits 22..15)   Pass B: t=8..15 (bits 14..7)
// Pass C: t=16..22 (bits 6..0) + bit-reversal scatter on the store.
// Radix-4 rounds: stage pair (t, t+1): e = j_t * 2^(21-t);
//   w1 = wt[2e] (stage t), w2a = wt[e] (t+1 lower), w2b = wt[e + 2^21] (t+1 upper)
// ---------------------------------------------------------------------------

__global__ __launch_bounds__(256) void fft_pass_a(const float* __restrict__ in,
                                                  const float2* __restrict__ wt,
                                                  float2* __restrict__ out)
{
    __shared__ float2 L[256 * 16];   // [g*16 + c]
    const int tid = threadIdx.x;
    const int l0  = blockIdx.x << 4;      // low-bit base (bits 14..0), 16 per WG

    // ---- load: real f32 input, imag = 0 ----
    {
        const int c4 = tid & 3;           // float4 slot (4 floats each)
        const int gg = tid >> 2;          // 0..63
#pragma unroll
        for (int k = 0; k < 4; ++k) {
            const int g = gg + (k << 6);
            const float4 v = *reinterpret_cast<const float4*>(in + ((size_t)g << 15) + l0 + (c4 << 2));
            const int base = (g << 4) + (c4 << 2);
            L[base + 0] = make_float2(v.x, 0.f);
            L[base + 1] = make_float2(v.y, 0.f);
            L[base + 2] = make_float2(v.z, 0.f);
            L[base + 3] = make_float2(v.w, 0.f);
        }
    }
    __syncthreads();

    // ---- stages 0..7 as 4 radix-4 rounds over g (strides 128..1) ----
    const int c  = tid & 15;
    const int qb = tid >> 4;              // 0..15
#pragma unroll
    for (int rho = 0; rho < 4; ++rho) {
        const int s  = rho << 1;          // local stage = global stage t
        const int H  = 128 >> s;
        const int Q  = H >> 1;
        const int lo = 6 - s;
#pragma unroll
        for (int k = 0; k < 4; ++k) {
            const int qi = (qb << 2) + k;                                   // 0..63
            const int b  = ((qi >> lo) << (lo + 2)) | (qi & ((1 << lo) - 1)); // H,Q bits clear
            const int jloc = s ? (int)(__brev((unsigned)(b >> (8 - s))) >> (32 - s)) : 0;
            const int e  = jloc << (21 - s);
            const float2 w2a = wt[e];
            const float2 w1  = wt[e << 1];
            const float2 w2b = wt[e + (1 << 21)];
            const int iA = (b << 4) + c;
            const float2 A  = L[iA];
            const float2 Bv = L[iA + (Q << 4)];
            const float2 Cv = L[iA + (H << 4)];
            const float2 Dv = L[iA + ((H + Q) << 4)];
            const float2 pC = cmul(w1, Cv), pD = cmul(w1, Dv);
            const float2 tA = cadd(A, pC),  tC = csub(A, pC);
            const float2 tB = cadd(Bv, pD), tD = csub(Bv, pD);
            const float2 p2 = cmul(w2a, tB);
            const float2 p3 = cmul(w2b, tD);
            L[iA]                  = cadd(tA, p2);
            L[iA + (Q << 4)]       = csub(tA, p2);
            L[iA + (H << 4)]       = cadd(tC, p3);
            L[iA + ((H + Q) << 4)] = csub(tC, p3);
        }
        __syncthreads();
    }

    // ---- store (same addresses, now complex) ----
    {
        const int c2 = tid & 7;           // complex-pair slot
        const int gg = tid >> 3;          // 0..31
#pragma unroll
        for (int k = 0; k < 8; ++k) {
            const int g  = gg + (k << 5);
            const int li = (g << 4) + (c2 << 1);
            const float2 a0 = L[li], a1 = L[li + 1];
            *reinterpret_cast<float4*>(out + ((size_t)g << 15) + l0 + (c2 << 1)) =
                make_float4(a0.x, a0.y, a1.x, a1.y);
        }
    }
}

__global__ __launch_bounds__(256) void fft_pass_b(const float2* __restrict__ in,
                                                  const float2* __restrict__ wt,
                                                  float2* __restrict__ out)
{
    __shared__ float2 L[256 * 16];   // [g*16 + c]
    const int tid  = threadIdx.x;
    const int h    = blockIdx.x >> 3;           // bits 22..15
    const int l0   = (blockIdx.x & 7) << 4;     // bits 6..0 base
    const size_t base = ((size_t)h << 15) + l0;
    const int hrev = (int)(__brev((unsigned)h) >> 24);  // rev8(h)

    // ---- load ----
    {
        const int c2 = tid & 7;
        const int gg = tid >> 3;          // 0..31
#pragma unroll
        for (int k = 0; k < 8; ++k) {
            const int g = gg + (k << 5);
            const float4 v = *reinterpret_cast<const float4*>(in + base + (g << 7) + (c2 << 1));
            const int li = (g << 4) + (c2 << 1);
            L[li]     = make_float2(v.x, v.y);
            L[li + 1] = make_float2(v.z, v.w);
        }
    }
    __syncthreads();

    // ---- stages 8..15 over g (addr bits 14..7) ----
    const int c  = tid & 15;
    const int qb = tid >> 4;
#pragma unroll
    for (int rho = 0; rho < 4; ++rho) {
        const int s  = rho << 1;          // global stage t = 8 + s
        const int H  = 128 >> s;
        const int Q  = H >> 1;
        const int lo = 6 - s;
#pragma unroll
        for (int k = 0; k < 4; ++k) {
            const int qi = (qb << 2) + k;
            const int b  = ((qi >> lo) << (lo + 2)) | (qi & ((1 << lo) - 1));
            const int jloc = s ? (int)(__brev((unsigned)(b >> (8 - s))) >> (32 - s)) : 0;
            const int e  = (hrev << (13 - s)) + (jloc << (21 - s));
            const float2 w2a = wt[e];
            const float2 w1  = wt[e << 1];
            const float2 w2b = wt[e + (1 << 21)];
            const int iA = (b << 4) + c;
            const float2 A  = L[iA];
            const float2 Bv = L[iA + (Q << 4)];
            const float2 Cv = L[iA + (H << 4)];
            const float2 Dv = L[iA + ((H + Q) << 4)];
            const float2 pC = cmul(w1, Cv), pD = cmul(w1, Dv);
            const float2 tA = cadd(A, pC),  tC = csub(A, pC);
            const float2 tB = cadd(Bv, pD), tD = csub(Bv, pD);
            const float2 p2 = cmul(w2a, tB);
            const float2 p3 = cmul(w2b, tD);
            L[iA]                  = cadd(tA, p2);
            L[iA + (Q << 4)]       = csub(tA, p2);
            L[iA + (H << 4)]       = cadd(tC, p3);
            L[iA + ((H + Q) << 4)] = csub(tC, p3);
        }
        __syncthreads();
    }

    // ---- store ----
    {
        const int c2 = tid & 7;
        const int gg = tid >> 3;
#pragma unroll
        for (int k = 0; k < 8; ++k) {
            const int g  = gg + (k << 5);
            const int li = (g << 4) + (c2 << 1);
            const float2 a0 = L[li], a1 = L[li + 1];
            *reinterpret_cast<float4*>(out + base + (g << 7) + (c2 << 1)) =
                make_float4(a0.x, a0.y, a1.x, a1.y);
        }
    }
}

__global__ __launch_bounds__(256) void fft_pass_c(const float2* __restrict__ in,
                                                  const float2* __restrict__ wt,
                                                  float2* __restrict__ out)
{
    __shared__ float2 L[64 * 129];    // [lam*129 + g], pitch 129 breaks bank conflicts
    const int tid = threadIdx.x;
    const int h0  = blockIdx.x;       // 0..1023

    // ---- load: 64 chunks of 128 contiguous complex; chunk id H = rev16(h0*64+lam) ----
    {
        const int f  = tid & 63;      // float4 slot within chunk
        const int ll = tid >> 6;      // 0..3
#pragma unroll
        for (int k = 0; k < 16; ++k) {
            const int lam = ll + (k << 2);
            const int H   = (int)(__brev((unsigned)((h0 << 6) + lam)) >> 16);
            const float4 v = *reinterpret_cast<const float4*>(in + ((size_t)H << 7) + (f << 1));
            const int li = lam * 129 + (f << 1);
            L[li]     = make_float2(v.x, v.y);
            L[li + 1] = make_float2(v.z, v.w);
        }
    }
    __syncthreads();

    // ---- stages 16..21 as 3 radix-4 rounds (g strides 64..2) ----
    const int lam = tid & 63;
    const int qh  = tid >> 6;                 // 0..3
    const int rH  = (h0 << 6) + lam;          // rev16(H) for this lane's chunk
#pragma unroll
    for (int rho = 0; rho < 3; ++rho) {
        const int s  = rho << 1;              // global stage t = 16 + s
        const int H  = 64 >> s;
        const int Q  = H >> 1;
        const int lo = 5 - s;
#pragma unroll
        for (int k = 0; k < 8; ++k) {
            const int qi = (qh << 3) + k;     // 0..31
            const int b  = ((qi >> lo) << (lo + 2)) | (qi & ((1 << lo) - 1));
            const int jloc = s ? (int)(__brev((unsigned)(b >> (7 - s))) >> (32 - s)) : 0;
            const int e  = (rH << (5 - s)) + (jloc << (21 - s));
            const float2 w2a = wt[e];
            const float2 w1  = wt[e << 1];
            const float2 w2b = wt[e + (1 << 21)];
            const int iA = lam * 129 + b;
            const float2 A  = L[iA];
            const float2 Bv = L[iA + Q];
            const float2 Cv = L[iA + H];
            const float2 Dv = L[iA + H + Q];
            const float2 pC = cmul(w1, Cv), pD = cmul(w1, Dv);
            const float2 tA = cadd(A, pC),  tC = csub(A, pC);
            const float2 tB = cadd(Bv, pD), tD = csub(Bv, pD);
            const float2 p2 = cmul(w2a, tB);
            const float2 p3 = cmul(w2b, tD);
            L[iA]         = cadd(tA, p2);
            L[iA + Q]     = csub(tA, p2);
            L[iA + H]     = cadd(tC, p3);
            L[iA + H + Q] = csub(tC, p3);
        }
        __syncthreads();
    }

    // ---- final radix-2 stage (t=22, stride 1) ----
    {
#pragma unroll
        for (int k = 0; k < 16; ++k) {
            const int pb   = (qh << 4) + k;   // 0..63
            const int b    = pb << 1;
            const int jloc = (int)(__brev((unsigned)pb) >> 26);  // rev6(b>>1)
            const float2 w = wt[rH + (jloc << 16)];
            const int iA = lam * 129 + b;
            const float2 A  = L[iA];
            const float2 Bv = L[iA + 1];
            const float2 p  = cmul(w, Bv);
            L[iA]     = cadd(A, p);
            L[iA + 1] = csub(A, p);
        }
    }
    __syncthreads();

    // ---- store with bit-reversal: out[rev7(g)*2^16 + h0*64 + lam] = L[lam][g] ----
    {
        const int l2 = (tid & 31) << 1;       // even lambda
        const int gb = tid >> 5;              // 0..7
#pragma unroll
        for (int k = 0; k < 16; ++k) {
            const int g    = gb + (k << 3);   // 0..127
            const int grev = (int)(__brev((unsigned)g) >> 25);   // rev7(g)
            const float2 a0 = L[l2 * 129 + g];
            const float2 a1 = L[(l2 + 1) * 129 + g];
            const size_t o = ((size_t)grev << 16) + (h0 << 6) + l2;
            *reinterpret_cast<float4*>(out + o) = make_float4(a0.x, a0.y, a1.x, a1.y);
        }
    }
}

extern "C" void kernel_launch(void* const* d_in, const int* in_sizes, int n_in,
                              void* d_out, int out_size, void* d_ws, size_t ws_size,
                              hipStream_t stream)
{
    (void)in_sizes; (void)n_in; (void)out_size; (void)ws_size;
    const float*  in = (const float*)d_in[0];
    const float2* wt = (const float2*)d_in[1];   // (2^22, 2) f32 -> complex
    float2* outc = (float2*)d_out;               // 2^23 complex
    float2* wsc  = (float2*)d_ws;                // needs 64 MB scratch

    fft_pass_a<<<2048, 256, 0, stream>>>(in, wt, outc);   // stages 0..7  : in  -> out
    fft_pass_b<<<2048, 256, 0, stream>>>(outc, wt, wsc);  // stages 8..15 : out -> ws
    fft_pass_c<<<1024, 256, 0, stream>>>(wsc, wt, outc);  // stages 16..22: ws  -> out (+bitrev)
}

// Round 2
// 198.575 us; speedup vs baseline: 1.0456x; 1.0456x over previous
//
#include <hip/hip_runtime.h>

__device__ __forceinline__ float2 cadd(float2 a, float2 b) { return make_float2(a.x + b.x, a.y + b.y); }
__device__ __forceinline__ float2 csub(float2 a, float2 b) { return make_float2(a.x - b.x, a.y - b.y); }
__device__ __forceinline__ float2 cmul(float2 w, float2 z) {
    return make_float2(w.x * z.x - w.y * z.y, w.x * z.y + w.y * z.x);
}

// In-place butterfly network equivalent of the reference:
//   stage t (0..22): pairs (i, i + 2^(22-t)); z'[i] = z[i] + w*z[i+D]; z'[i+D] = z[i] - w*z[i+D]
//   w = weight[ bitrev_t(i >> (23-t)) * 2^(22-t) ];  final: out[o] = z[bitrev23(o)]
// Pass A: t=0..7 (bits 22..15) | Pass B: t=8..15 (bits 14..7) | Pass C: t=16..22 (bits 6..0) + bitrev store.
// Weight regs are software-pipelined: round rho+1's weights load during round rho.

__global__ __launch_bounds__(256) void fft_pass_a(const float* __restrict__ in,
                                                  const float2* __restrict__ wt,
                                                  float2* __restrict__ out)
{
    __shared__ float2 L[4096];   // [g*16 + c], 32 KB
    const int tid = threadIdx.x;
    const int l0  = blockIdx.x << 4;
    const int c   = tid & 15;
    const int qb  = tid >> 4;

    // prefetch round-0 weights (s=0 -> jloc=0, e=0), k-uniform
    float2 pw1[4], pw2a[4], pw2b[4];
#pragma unroll
    for (int k = 0; k < 4; ++k) { pw1[k] = wt[0]; pw2a[k] = wt[0]; pw2b[k] = wt[1 << 21]; }

    // ---- load: real input, imag = 0 ----
    {
        const int c4 = tid & 3, gg = tid >> 2;
#pragma unroll
        for (int k = 0; k < 4; ++k) {
            const int g = gg + (k << 6);
            const float4 v = *reinterpret_cast<const float4*>(in + ((size_t)g << 15) + l0 + (c4 << 2));
            const int base = (g << 4) + (c4 << 2);
            L[base + 0] = make_float2(v.x, 0.f);
            L[base + 1] = make_float2(v.y, 0.f);
            L[base + 2] = make_float2(v.z, 0.f);
            L[base + 3] = make_float2(v.w, 0.f);
        }
    }
    __syncthreads();

#pragma unroll
    for (int rho = 0; rho < 4; ++rho) {
        const int s = rho << 1, H = 128 >> s, Q = H >> 1, lo = 6 - s;
        float2 nw1[4], nw2a[4], nw2b[4];
        if (rho < 3) {                       // prefetch next round's weights
            const int s2 = s + 2, lo2 = 6 - s2;
#pragma unroll
            for (int k = 0; k < 4; ++k) {
                const int qi = (qb << 2) + k;
                const int b  = ((qi >> lo2) << (lo2 + 2)) | (qi & ((1 << lo2) - 1));
                const int jl = (int)(__brev((unsigned)(b >> (8 - s2))) >> (32 - s2));
                const int e  = jl << (21 - s2);
                nw1[k] = wt[e << 1]; nw2a[k] = wt[e]; nw2b[k] = wt[e + (1 << 21)];
            }
        }
#pragma unroll
        for (int k = 0; k < 4; ++k) {
            const int qi = (qb << 2) + k;
            const int b  = ((qi >> lo) << (lo + 2)) | (qi & ((1 << lo) - 1));
            const int iA = (b << 4) + c;
            const float2 A  = L[iA];
            const float2 Bv = L[iA + (Q << 4)];
            const float2 Cv = L[iA + (H << 4)];
            const float2 Dv = L[iA + ((H + Q) << 4)];
            const float2 pC = cmul(pw1[k], Cv), pD = cmul(pw1[k], Dv);
            const float2 tA = cadd(A, pC),  tC = csub(A, pC);
            const float2 tB = cadd(Bv, pD), tD = csub(Bv, pD);
            const float2 p2 = cmul(pw2a[k], tB);
            const float2 p3 = cmul(pw2b[k], tD);
            L[iA]                  = cadd(tA, p2);
            L[iA + (Q << 4)]       = csub(tA, p2);
            L[iA + (H << 4)]       = cadd(tC, p3);
            L[iA + ((H + Q) << 4)] = csub(tC, p3);
        }
        __syncthreads();
        if (rho < 3) {
#pragma unroll
            for (int k = 0; k < 4; ++k) { pw1[k] = nw1[k]; pw2a[k] = nw2a[k]; pw2b[k] = nw2b[k]; }
        }
    }

    // ---- store ----
    {
        const int c2 = tid & 7, gg = tid >> 3;
#pragma unroll
        for (int k = 0; k < 8; ++k) {
            const int g  = gg + (k << 5);
            const int li = (g << 4) + (c2 << 1);
            const float2 a0 = L[li], a1 = L[li + 1];
            *reinterpret_cast<float4*>(out + ((size_t)g << 15) + l0 + (c2 << 1)) =
                make_float4(a0.x, a0.y, a1.x, a1.y);
        }
    }
}

__global__ __launch_bounds__(256) void fft_pass_b(const float2* __restrict__ in,
                                                  const float2* __restrict__ wt,
                                                  float2* __restrict__ out)
{
    __shared__ float2 L[4096];   // 32 KB
    const int tid  = threadIdx.x;
    const int h    = blockIdx.x >> 3;
    const int l0   = (blockIdx.x & 7) << 4;
    const size_t base = ((size_t)h << 15) + l0;
    const int hrev = (int)(__brev((unsigned)h) >> 24);
    const int c  = tid & 15;
    const int qb = tid >> 4;

    // prefetch round-0 weights (s=0 -> e = hrev<<13), k-uniform
    float2 pw1[4], pw2a[4], pw2b[4];
    {
        const int e0 = hrev << 13;
#pragma unroll
        for (int k = 0; k < 4; ++k) { pw1[k] = wt[e0 << 1]; pw2a[k] = wt[e0]; pw2b[k] = wt[e0 + (1 << 21)]; }
    }

    // ---- load ----
    {
        const int c2 = tid & 7, gg = tid >> 3;
#pragma unroll
        for (int k = 0; k < 8; ++k) {
            const int g = gg + (k << 5);
            const float4 v = *reinterpret_cast<const float4*>(in + base + (g << 7) + (c2 << 1));
            const int li = (g << 4) + (c2 << 1);
            L[li]     = make_float2(v.x, v.y);
            L[li + 1] = make_float2(v.z, v.w);
        }
    }
    __syncthreads();

#pragma unroll
    for (int rho = 0; rho < 4; ++rho) {
        const int s = rho << 1, H = 128 >> s, Q = H >> 1, lo = 6 - s;
        float2 nw1[4], nw2a[4], nw2b[4];
        if (rho < 3) {
            const int s2 = s + 2, lo2 = 6 - s2;
#pragma unroll
            for (int k = 0; k < 4; ++k) {
                const int qi = (qb << 2) + k;
                const int b  = ((qi >> lo2) << (lo2 + 2)) | (qi & ((1 << lo2) - 1));
                const int jl = (int)(__brev((unsigned)(b >> (8 - s2))) >> (32 - s2));
                const int e  = (hrev << (13 - s2)) + (jl << (21 - s2));
                nw1[k] = wt[e << 1]; nw2a[k] = wt[e]; nw2b[k] = wt[e + (1 << 21)];
            }
        }
#pragma unroll
        for (int k = 0; k < 4; ++k) {
            const int qi = (qb << 2) + k;
            const int b  = ((qi >> lo) << (lo + 2)) | (qi & ((1 << lo) - 1));
            const int iA = (b << 4) + c;
            const float2 A  = L[iA];
            const float2 Bv = L[iA + (Q << 4)];
            const float2 Cv = L[iA + (H << 4)];
            const float2 Dv = L[iA + ((H + Q) << 4)];
            const float2 pC = cmul(pw1[k], Cv), pD = cmul(pw1[k], Dv);
            const float2 tA = cadd(A, pC),  tC = csub(A, pC);
            const float2 tB = cadd(Bv, pD), tD = csub(Bv, pD);
            const float2 p2 = cmul(pw2a[k], tB);
            const float2 p3 = cmul(pw2b[k], tD);
            L[iA]                  = cadd(tA, p2);
            L[iA + (Q << 4)]       = csub(tA, p2);
            L[iA + (H << 4)]       = cadd(tC, p3);
            L[iA + ((H + Q) << 4)] = csub(tC, p3);
        }
        __syncthreads();
        if (rho < 3) {
#pragma unroll
            for (int k = 0; k < 4; ++k) { pw1[k] = nw1[k]; pw2a[k] = nw2a[k]; pw2b[k] = nw2b[k]; }
        }
    }

    // ---- store ----
    {
        const int c2 = tid & 7, gg = tid >> 3;
#pragma unroll
        for (int k = 0; k < 8; ++k) {
            const int g  = gg + (k << 5);
            const int li = (g << 4) + (c2 << 1);
            const float2 a0 = L[li], a1 = L[li + 1];
            *reinterpret_cast<float4*>(out + base + (g << 7) + (c2 << 1)) =
                make_float4(a0.x, a0.y, a1.x, a1.y);
        }
    }
}

__global__ __launch_bounds__(256) void fft_pass_c(const float2* __restrict__ in,
                                                  const float2* __restrict__ wt,
                                                  float2* __restrict__ out)
{
    __shared__ float2 L[32 * 129];    // 32 chunks, pitch 129 -> ~33 KB (4 blocks/CU)
    const int tid = threadIdx.x;
    const int h0  = blockIdx.x;       // 0..2047

    // compute-phase lane map: lam in LOW lane bits -> late-stage weight reads coalesce over rH
    const int lam = tid & 31;
    const int bq  = tid >> 5;         // 0..7
    const int rH  = (h0 << 5) + lam;  // rev16(H) for this lane's chunk

    // prefetch round-0 weights (s=0 -> jloc=0, e = rH<<5), k-uniform
    float2 pw1[4], pw2a[4], pw2b[4];
#pragma unroll
    for (int k = 0; k < 4; ++k) {
        pw1[k]  = wt[rH << 6];
        pw2a[k] = wt[rH << 5];
        pw2b[k] = wt[(rH << 5) + (1 << 21)];
    }

    // ---- load: 32 chunks of 128 contiguous complex; chunk id H = rev16(h0*32+lam') ----
    {
        const int f  = tid & 63;      // float4 slot within chunk (wave = 1 KB contiguous)
        const int ll = tid >> 6;      // 0..3
#pragma unroll
        for (int k = 0; k < 8; ++k) {
            const int lm = ll + (k << 2);
            const int H  = (int)(__brev((unsigned)((h0 << 5) + lm)) >> 16);
            const float4 v = *reinterpret_cast<const float4*>(in + ((size_t)H << 7) + (f << 1));
            const int li = lm * 129 + (f << 1);
            L[li]     = make_float2(v.x, v.y);
            L[li + 1] = make_float2(v.z, v.w);
        }
    }
    __syncthreads();

    // ---- stages 16..21 as 3 radix-4 rounds ----
    float2 pr2[8];
#pragma unroll
    for (int rho = 0; rho < 3; ++rho) {
        const int s = rho << 1, H = 64 >> s, Q = H >> 1, lo = 5 - s;
        float2 nw1[4], nw2a[4], nw2b[4];
        if (rho < 2) {                       // prefetch next radix-4 round
            const int s2 = s + 2, lo2 = 5 - s2;
#pragma unroll
            for (int k = 0; k < 4; ++k) {
                const int qi = (bq << 2) + k;
                const int b  = ((qi >> lo2) << (lo2 + 2)) | (qi & ((1 << lo2) - 1));
                const int jl = (int)(__brev((unsigned)(b >> (7 - s2))) >> (32 - s2));
                const int e  = (rH << (5 - s2)) + (jl << (21 - s2));
                nw1[k] = wt[e << 1]; nw2a[k] = wt[e]; nw2b[k] = wt[e + (1 << 21)];
            }
        } else {                             // prefetch final radix-2 weights
#pragma unroll
            for (int k = 0; k < 8; ++k) {
                const int pb = (bq << 3) + k;
                const int jl = (int)(__brev((unsigned)pb) >> 26);
                pr2[k] = wt[rH + (jl << 16)];
            }
        }
#pragma unroll
        for (int k = 0; k < 4; ++k) {
            const int qi = (bq << 2) + k;
            const int b  = ((qi >> lo) << (lo + 2)) | (qi & ((1 << lo) - 1));
            const int iA = lam * 129 + b;
            const float2 A  = L[iA];
            const float2 Bv = L[iA + Q];
            const float2 Cv = L[iA + H];
            const float2 Dv = L[iA + H + Q];
            const float2 pC = cmul(pw1[k], Cv), pD = cmul(pw1[k], Dv);
            const float2 tA = cadd(A, pC),  tC = csub(A, pC);
            const float2 tB = cadd(Bv, pD), tD = csub(Bv, pD);
            const float2 p2 = cmul(pw2a[k], tB);
            const float2 p3 = cmul(pw2b[k], tD);
            L[iA]         = cadd(tA, p2);
            L[iA + Q]     = csub(tA, p2);
            L[iA + H]     = cadd(tC, p3);
            L[iA + H + Q] = csub(tC, p3);
        }
        __syncthreads();
        if (rho < 2) {
#pragma unroll
            for (int k = 0; k < 4; ++k) { pw1[k] = nw1[k]; pw2a[k] = nw2a[k]; pw2b[k] = nw2b[k]; }
        }
    }

    // ---- final radix-2 stage (t=22, stride 1) ----
    {
#pragma unroll
        for (int k = 0; k < 8; ++k) {
            const int pb = (bq << 3) + k;
            const int b  = pb << 1;
            const int iA = lam * 129 + b;
            const float2 A  = L[iA];
            const float2 Bv = L[iA + 1];
            const float2 p  = cmul(pr2[k], Bv);
            L[iA]     = cadd(A, p);
            L[iA + 1] = csub(A, p);
        }
    }
    __syncthreads();

    // ---- store with bit-reversal: out[rev7(g)*2^16 + h0*32 + lam] = L[lam][g] ----
    {
        const int l2 = (tid & 15) << 1;       // even lam
        const int gb = tid >> 4;              // 0..15
#pragma unroll
        for (int k = 0; k < 8; ++k) {
            const int g    = gb + (k << 4);   // 0..127
            const int grev = (int)(__brev((unsigned)g) >> 25);   // rev7(g)
            const float2 a0 = L[l2 * 129 + g];
            const float2 a1 = L[(l2 + 1) * 129 + g];
            const size_t o = ((size_t)grev << 16) + (h0 << 5) + l2;
            *reinterpret_cast<float4*>(out + o) = make_float4(a0.x, a0.y, a1.x, a1.y);
        }
    }
}

extern "C" void kernel_launch(void* const* d_in, const int* in_sizes, int n_in,
                              void* d_out, int out_size, void* d_ws, size_t ws_size,
                              hipStream_t stream)
{
    (void)in_sizes; (void)n_in; (void)out_size; (void)ws_size;
    const float*  in = (const float*)d_in[0];
    const float2* wt = (const float2*)d_in[1];
    float2* outc = (float2*)d_out;
    float2* wsc  = (float2*)d_ws;

    fft_pass_a<<<2048, 256, 0, stream>>>(in, wt, outc);   // stages 0..7  : in  -> out
    fft_pass_b<<<2048, 256, 0, stream>>>(outc, wt, wsc);  // stages 8..15 : out -> ws
    fft_pass_c<<<2048, 256, 0, stream>>>(wsc, wt, outc);  // stages 16..22: ws  -> out (+bitrev)
}